// Round 14
// baseline (413.142 us; speedup 1.0000x reference)
//
#include <hip/hip_runtime.h>
#include <cstddef>

typedef _Float16 f16x8 __attribute__((ext_vector_type(8)));
typedef _Float16 f16x4 __attribute__((ext_vector_type(4)));
typedef __fp16 h16x2 __attribute__((ext_vector_type(2)));   // cvt_pkrtz result type
typedef float f32x4 __attribute__((ext_vector_type(4)));
typedef float f32x16 __attribute__((ext_vector_type(16)));

// Problem constants
constexpr int BATCH = 128;
constexpr int T     = 16;
constexpr int ROWS  = BATCH * T * T;  // 32768
constexpr int WID   = 100;
constexpr int NB    = 50;
constexpr int KP    = 128;            // LDS k-stride (pow2 for swizzle)
constexpr int KS    = 7;              // k-steps of 16 -> K=112 >= 100
constexpr int NP    = 128;            // padded N (4 col-tiles of 32)
constexpr int RPW   = 64;             // rows per workgroup
constexpr int WCH   = KS * 4 * 512;   // 14336 f16 per fragment-imaged matrix

// ---------------------------------------------------------------------------
// Prep: split weights into f16 hi/lo in 32x32x16 A-fragment stream order.
// Chunk (bk*2+m, ks, ct) is 1KB: lane L, elem i ->
//   W[k = 16*ks + 8*(L>>5) + i][j = 32*ct + (L&31)], zero-padded.
// Epilogue-fold constants: c1 = b1*colsum(Wa) + b2/2 ; c2 = m*b3*colsum(Wb)+b4;
// S = 4m.  (v = 4*relu(x@Wa + c1) + b3 ; x' = relu(x + S*(u@Wb) + c2))
// ---------------------------------------------------------------------------
__global__ __launch_bounds__(256) void prep_kernel(
    const float* __restrict__ Wa, const float* __restrict__ Wb,
    const float* __restrict__ B1, const float* __restrict__ B2,
    const float* __restrict__ B3, const float* __restrict__ B4,
    const float* __restrict__ M,
    _Float16* __restrict__ whi, _Float16* __restrict__ wlo,
    float* __restrict__ c1, float* __restrict__ c2, float* __restrict__ S) {
  const int bid = blockIdx.x;          // 0..99 = bk*2 + m
  const int bk = bid >> 1, m = bid & 1;
  const float* src = (m ? Wb : Wa) + (size_t)bk * (WID * WID);
  _Float16* dh = whi + (size_t)bid * WCH;
  _Float16* dl = wlo + (size_t)bid * WCH;
  for (int e = threadIdx.x; e < WCH; e += 256) {
    const int i  = e & 7;
    const int L  = (e >> 3) & 63;
    const int ct = (e >> 9) & 3;
    const int ks = e >> 11;
    const int k  = 16 * ks + 8 * (L >> 5) + i;
    const int j  = 32 * ct + (L & 31);
    const float v = (k < WID && j < WID) ? src[k * WID + j] : 0.0f;
    const _Float16 hi = (_Float16)v;
    dh[e] = hi;
    dl[e] = (_Float16)(v - (float)hi);
  }
  for (int col = threadIdx.x; col < NP; col += 256) {
    float s = 0.0f;
    if (col < WID) {
      for (int k = 0; k < WID; ++k) s += src[k * WID + col];
    }
    if (!m) {
      c1[bk * NP + col] = B1[bk] * s + 0.5f * B2[bk];
    } else {
      c2[bk * NP + col] = M[bk] * B3[bk] * s + B4[bk];
    }
  }
  if (!m && threadIdx.x == 0) S[bk] = 4.0f * M[bk];
}

// ---------------------------------------------------------------------------
// First layer: gather 45-wide stencil rows, x0 = relu(flat @ W0)
// ---------------------------------------------------------------------------
__global__ __launch_bounds__(256) void first_layer_kernel(
    const float* __restrict__ inp, const float* __restrict__ W0,
    float* __restrict__ x0) {
  __shared__ float w0s[45 * WID];
  for (int i = threadIdx.x; i < 45 * WID; i += 256) w0s[i] = W0[i];
  __syncthreads();

  const int rq  = threadIdx.x >> 2;
  const int cq  = threadIdx.x & 3;
  const int row = blockIdx.x * 64 + rq;
  const int b   = row >> 8;
  const int t1  = (row >> 4) & 15;
  const int t2  = row & 15;
  const int g1  = 2 * t1, g2 = 2 * t2;
  const int g1m = (g1 + 31) & 31, g2m = (g2 + 31) & 31;
  const float* base = inp + (size_t)b * (32 * 32 * 9);
  const float* p0 = base + ((g1 + 1) * 32 + g2) * 9;
  const float* p1 = base + (g1m * 32 + g2) * 9;
  const float* p2 = base + (g1 * 32 + (g2 + 1)) * 9;
  const float* p3 = base + (g1 * 32 + g2m) * 9;
  const float* p4 = base + (g1 * 32 + g2) * 9;

  float f[45];
#pragma unroll
  for (int qq = 0; qq < 9; ++qq) {
    f[qq]      = p0[qq];
    f[9 + qq]  = p1[qq];
    f[18 + qq] = p2[qq];
    f[27 + qq] = p3[qq];
    f[36 + qq] = p4[qq];
  }

  float acc[25];
#pragma unroll
  for (int j = 0; j < 25; ++j) acc[j] = 0.0f;
  const int j0 = cq * 25;
#pragma unroll
  for (int k = 0; k < 45; ++k) {
    const float fv = f[k];
#pragma unroll
    for (int j = 0; j < 25; ++j) acc[j] += fv * w0s[k * WID + j0 + j];
  }
  float* orow = x0 + (size_t)row * WID + j0;
#pragma unroll
  for (int j = 0; j < 25; ++j) orow[j] = fmaxf(acc[j], 0.0f);
}

// ---------------------------------------------------------------------------
// Chain: 50 residual blocks, split-f16 MFMA 32x32x16 (f32 accum, ~2^-22).
// 512 WGs x 512 thr (8 waves) -> 2 WG/CU, 16 waves/CU (VGPR<=64 critical:
// weight regs live ONLY inside kloop, never across a barrier -- R12 lesson).
// Wave (rt,ct) owns rows [32rt,+32) x cols [32ct,+32); acc = f32x16.
// LDS: x hi/lo + u hi/lo, f16 [64][128], swizzle k ^ ((row&15)<<3).
// GEMM1 acc pre-initialized with c1 (bias folded into accumulator init).
// s_setprio(1) around the MFMA cluster (T5; 2 drifting WGs = role diversity).
// ---------------------------------------------------------------------------
__global__ __launch_bounds__(512, 2) void chain_kernel(
    float* __restrict__ x0,
    const _Float16* __restrict__ whi, const _Float16* __restrict__ wlo,
    const float* __restrict__ c1, const float* __restrict__ c2,
    const float* __restrict__ S) {
  __shared__ __align__(16) _Float16 xhs[RPW * KP];   // 16 KB
  __shared__ __align__(16) _Float16 xls[RPW * KP];   // 16 KB
  __shared__ __align__(16) _Float16 vhs[RPW * KP];   // 16 KB
  __shared__ __align__(16) _Float16 vls[RPW * KP];   // 16 KB

  const int tid  = threadIdx.x;
  const int lane = tid & 63;
  const int uw   = __builtin_amdgcn_readfirstlane(tid >> 6);  // wave 0..7
  const int rt   = uw >> 2;     // row-tile 0..1
  const int ct   = uw & 3;      // col-tile 0..3
  const int jr   = lane & 31;   // x-row within tile / w-col lane
  const int kg   = lane >> 5;   // k-group 0..1
  const int rbase = blockIdx.x * RPW;

  const int row_x = 32 * rt + jr;            // this lane's x-row
  const int sw    = (row_x & 15) << 3;       // XOR swizzle (f16 units)

  // fill x hi/lo (f32 -> split f16, swizzled); k >= 100 zeroed
  for (int i = tid; i < RPW * KP; i += 512) {
    const int row = i >> 7, k = i & 127;
    const float v = (k < WID) ? x0[(size_t)(rbase + row) * WID + k] : 0.0f;
    const _Float16 hi = (_Float16)v;
    const int a = row * KP + (k ^ ((row & 15) << 3));
    xhs[a] = hi;
    xls[a] = (_Float16)(v - (float)hi);
  }

  // output j coordinates: j = j0g[g] + r, 4 groups of 4 consecutive
  int j0g[4];
#pragma unroll
  for (int g = 0; g < 4; ++g) j0g[g] = 32 * ct + 4 * kg + 8 * g;

  // fp32 residual state: 4 x f32x4 (row fixed = row_x)
  f32x4 xres[4];
#pragma unroll
  for (int g = 0; g < 4; ++g) {
    if (j0g[g] <= WID - 4) {
      xres[g] = *(const f32x4*)&x0[(size_t)(rbase + row_x) * WID + j0g[g]];
    } else {
      xres[g] = (f32x4){0.f, 0.f, 0.f, 0.f};
    }
  }
  __syncthreads();

  f32x16 acc;

  // split-f16 GEMM tile: acc += (wh+wl)^T @ (xh+xl), dropping wl*xl.
  // Weight loads batched at kloop top; registers dead at kloop exit.
  auto kloop = [&](const int gidx,
                   const _Float16* __restrict__ xhsrc,
                   const _Float16* __restrict__ xlsrc) {
    const _Float16* gh = whi + (size_t)gidx * WCH + ct * 512;
    const _Float16* gl = wlo + (size_t)gidx * WCH + ct * 512;
    f16x8 wh[KS], wl[KS];
#pragma unroll
    for (int ks = 0; ks < KS; ++ks) {
      wh[ks] = *(const f16x8*)&gh[ks * 2048 + lane * 8];
      wl[ks] = *(const f16x8*)&gl[ks * 2048 + lane * 8];
    }
    __builtin_amdgcn_s_setprio(1);
#pragma unroll
    for (int ks = 0; ks < KS; ++ks) {
      const int off = row_x * KP + ((16 * ks + 8 * kg) ^ sw);
      const f16x8 xh = *(const f16x8*)&xhsrc[off];
      const f16x8 xl = *(const f16x8*)&xlsrc[off];
      acc = __builtin_amdgcn_mfma_f32_32x32x16_f16(wh[ks], xh, acc, 0, 0, 0);
      acc = __builtin_amdgcn_mfma_f32_32x32x16_f16(wl[ks], xh, acc, 0, 0, 0);
      acc = __builtin_amdgcn_mfma_f32_32x32x16_f16(wh[ks], xl, acc, 0, 0, 0);
    }
    __builtin_amdgcn_s_setprio(0);
  };

  for (int bk = 0; bk < NB; ++bk) {
    // ---------------- GEMM1: u = relu(x@Wa + c1), c1 in acc-init ----------
#pragma unroll
    for (int g = 0; g < 4; ++g) {
      const f32x4 c1v = *(const f32x4*)&c1[bk * NP + j0g[g]];
      acc[g * 4 + 0] = c1v[0];
      acc[g * 4 + 1] = c1v[1];
      acc[g * 4 + 2] = c1v[2];
      acc[g * 4 + 3] = c1v[3];
    }
    kloop(bk * 2, xhs, xls);
#pragma unroll
    for (int g = 0; g < 4; ++g) {
      const float u0 = fmaxf(acc[g * 4 + 0], 0.0f);
      const float u1 = fmaxf(acc[g * 4 + 1], 0.0f);
      const float u2 = fmaxf(acc[g * 4 + 2], 0.0f);
      const float u3 = fmaxf(acc[g * 4 + 3], 0.0f);
      const h16x2 h01 = __builtin_amdgcn_cvt_pkrtz(u0, u1);
      const h16x2 h23 = __builtin_amdgcn_cvt_pkrtz(u2, u3);
      const h16x2 l01 = __builtin_amdgcn_cvt_pkrtz(u0 - (float)h01[0],
                                                   u1 - (float)h01[1]);
      const h16x2 l23 = __builtin_amdgcn_cvt_pkrtz(u2 - (float)h23[0],
                                                   u3 - (float)h23[1]);
      f16x4 hv, lv;
      *(h16x2*)&hv = h01; *((h16x2*)&hv + 1) = h23;
      *(h16x2*)&lv = l01; *((h16x2*)&lv + 1) = l23;
      const int a = row_x * KP + (j0g[g] ^ sw);
      *(f16x4*)&vhs[a] = hv;
      *(f16x4*)&vls[a] = lv;
    }
    __syncthreads();            // publish u (x-reads of kloop1 also done)

    // ---------------- GEMM2: x = relu(x + S*(u@Wb) + c2) -------------------
#pragma unroll
    for (int e = 0; e < 16; ++e) acc[e] = 0.0f;
    kloop(bk * 2 + 1, vhs, vls);
    {
      const float s = S[bk];
#pragma unroll
      for (int g = 0; g < 4; ++g) {
        const f32x4 c2v = *(const f32x4*)&c2[bk * NP + j0g[g]];
        float n0 = fmaxf(xres[g][0] + fmaf(acc[g * 4 + 0], s, c2v[0]), 0.0f);
        float n1 = fmaxf(xres[g][1] + fmaf(acc[g * 4 + 1], s, c2v[1]), 0.0f);
        float n2 = fmaxf(xres[g][2] + fmaf(acc[g * 4 + 2], s, c2v[2]), 0.0f);
        float n3 = fmaxf(xres[g][3] + fmaf(acc[g * 4 + 3], s, c2v[3]), 0.0f);
        xres[g][0] = n0; xres[g][1] = n1; xres[g][2] = n2; xres[g][3] = n3;
        const h16x2 h01 = __builtin_amdgcn_cvt_pkrtz(n0, n1);
        const h16x2 h23 = __builtin_amdgcn_cvt_pkrtz(n2, n3);
        const h16x2 l01 = __builtin_amdgcn_cvt_pkrtz(n0 - (float)h01[0],
                                                     n1 - (float)h01[1]);
        const h16x2 l23 = __builtin_amdgcn_cvt_pkrtz(n2 - (float)h23[0],
                                                     n3 - (float)h23[1]);
        f16x4 hv, lv;
        *(h16x2*)&hv = h01; *((h16x2*)&hv + 1) = h23;
        *(h16x2*)&lv = l01; *((h16x2*)&lv + 1) = l23;
        const int a = row_x * KP + (j0g[g] ^ sw);
        *(f16x4*)&xhs[a] = hv;
        *(f16x4*)&xls[a] = lv;
      }
    }
    __syncthreads();            // publish x(bk+1)
  }

  // write back fp32 residual state
#pragma unroll
  for (int g = 0; g < 4; ++g) {
    if (j0g[g] <= WID - 4)
      *(f32x4*)&x0[(size_t)(rbase + row_x) * WID + j0g[g]] = xres[g];
  }
}

// ---------------------------------------------------------------------------
// Output head + stencil epilogue. One block per batch image (16x16 grid).
// ---------------------------------------------------------------------------
__global__ __launch_bounds__(256) void out_kernel(
    const float* __restrict__ inp, const float* __restrict__ x0,
    const float* __restrict__ Wout, const float* __restrict__ bout,
    float* __restrict__ out) {
  __shared__ float ys[256 * 4];
  __shared__ float wouts[WID * 4];
  __shared__ float bos[4];
  const int tid = threadIdx.x;
  const int b   = blockIdx.x;

  for (int i = tid; i < WID * 4; i += 256) wouts[i] = Wout[i];
  if (tid < 4) bos[tid] = bout[tid];
  __syncthreads();

  const int row = b * 256 + tid;
  const float* xr = x0 + (size_t)row * WID;
  float a0 = 0.f, a1 = 0.f, a2 = 0.f, a3 = 0.f;
#pragma unroll 4
  for (int k = 0; k < WID; ++k) {
    const float xv = xr[k];
    a0 += xv * wouts[k * 4 + 0];
    a1 += xv * wouts[k * 4 + 1];
    a2 += xv * wouts[k * 4 + 2];
    a3 += xv * wouts[k * 4 + 3];
  }
  ys[tid * 4 + 0] = a0 + bos[0];
  ys[tid * 4 + 1] = a1 + bos[1];
  ys[tid * 4 + 2] = a2 + bos[2];
  ys[tid * 4 + 3] = a3 + bos[3];
  __syncthreads();

  const int i = tid >> 4, j = tid & 15;
  const int ip1 = (i + 1) & 15, im1 = (i + 15) & 15;
  const int jp1 = (j + 1) & 15, jm1 = (j + 15) & 15;
  auto Y = [&](int a, int c, int comp) { return ys[(((a << 4) | c) << 2) + comp]; };
  const float y0 = Y(i, j, 0), y1 = Y(i, j, 1), y2 = Y(i, j, 2), y3 = Y(i, j, 3);
  const float right_c = y0 / (Y(ip1, j, 1) + y0);
  const float left_c  = y1 / (y1 + Y(im1, j, 0));
  const float up_c    = y2 / (y2 + Y(i, jp1, 3));
  const float down_c  = y3 / (Y(i, jm1, 2) + y3);

  const float* base = inp + (size_t)b * (32 * 32 * 9);
  const int g1 = 2 * i + 1, g1m = (2 * i + 31) & 31;
  const int g2 = 2 * j + 1, g2m = (2 * j + 31) & 31;
  const float* oo = base + (g1 * 32 + g2) * 9;
  const float* oi = base + (g1 * 32 + g2m) * 9;
  const float* io = base + (g1m * 32 + g2) * 9;
  const float* ii = base + (g1m * 32 + g2m) * 9;
  const float ru = -(oo[0] + oo[3] * right_c + oo[1] * up_c) / oo[4];
  const float rd = -(oi[2] + oi[5] * right_c + oi[1] * down_c) / oi[4];
  const float lu = -(io[6] + io[3] * left_c + io[7] * up_c) / io[4];
  const float ld = -(ii[8] + ii[5] * left_c + ii[7] * down_c) / ii[4];

  float* o = out + (size_t)row * 9;
  o[0] = ld;     o[1] = left_c;  o[2] = lu;
  o[3] = down_c; o[4] = 1.0f;    o[5] = up_c;
  o[6] = rd;     o[7] = right_c; o[8] = ru;
}

// ---------------------------------------------------------------------------
extern "C" void kernel_launch(void* const* d_in, const int* in_sizes, int n_in,
                              void* d_out, int out_size, void* d_ws, size_t ws_size,
                              hipStream_t stream) {
  const float* inp  = (const float*)d_in[0];
  const float* W0   = (const float*)d_in[1];
  const float* Wa   = (const float*)d_in[2];
  const float* Wb   = (const float*)d_in[3];
  const float* B1   = (const float*)d_in[4];
  const float* B2   = (const float*)d_in[5];
  const float* B3   = (const float*)d_in[6];
  const float* B4   = (const float*)d_in[7];
  const float* M    = (const float*)d_in[8];
  const float* Wout = (const float*)d_in[9];
  const float* bout = (const float*)d_in[10];
  float* out = (float*)d_out;

  float* ws     = (float*)d_ws;
  float* x0     = ws;                              // 3,276,800 f32
  _Float16* whi = (_Float16*)(ws + 3276800);       // 100*14336 f16 = 716,800 f32
  _Float16* wlo = (_Float16*)(ws + 3276800 + 716800);
  float* c1     = ws + 3276800 + 716800 + 716800;  // 50*128 f32
  float* c2     = c1 + 6400;                       // 50*128 f32
  float* S      = c2 + 6400;                       // 50 f32

  hipLaunchKernelGGL(prep_kernel, dim3(100), dim3(256), 0, stream,
                     Wa, Wb, B1, B2, B3, B4, M, whi, wlo, c1, c2, S);
  hipLaunchKernelGGL(first_layer_kernel, dim3(ROWS / 64), dim3(256), 0, stream,
                     inp, W0, x0);
  hipLaunchKernelGGL(chain_kernel, dim3(ROWS / RPW), dim3(512), 0, stream,
                     x0, whi, wlo, c1, c2, S);
  hipLaunchKernelGGL(out_kernel, dim3(BATCH), dim3(256), 0, stream,
                     inp, x0, Wout, bout, out);
}

// Round 15
// 328.298 us; speedup vs baseline: 1.2584x; 1.2584x over previous
//
#include <hip/hip_runtime.h>
#include <cstddef>

typedef _Float16 f16x8 __attribute__((ext_vector_type(8)));
typedef _Float16 f16x4 __attribute__((ext_vector_type(4)));
typedef float f32x4 __attribute__((ext_vector_type(4)));
typedef float f32x16 __attribute__((ext_vector_type(16)));

// Problem constants
constexpr int BATCH = 128;
constexpr int T     = 16;
constexpr int ROWS  = BATCH * T * T;  // 32768
constexpr int WID   = 100;
constexpr int NB    = 50;
constexpr int KP    = 128;            // LDS k-stride (pow2 for swizzle)
constexpr int KS    = 7;              // k-steps of 16 -> K=112 >= 100
constexpr int NP    = 128;            // padded N (4 col-tiles of 32)
constexpr int RPW   = 64;             // rows per workgroup
constexpr int WCH   = KS * 4 * 512;   // 14336 f16 per fragment-imaged matrix

// ---------------------------------------------------------------------------
// Prep: split weights into f16 hi/lo in 32x32x16 A-fragment stream order.
// Chunk (bk*2+m, ks, ct) is 1KB: lane L, elem i ->
//   W[k = 16*ks + 8*(L>>5) + i][j = 32*ct + (L&31)], zero-padded.
// Also colsum of Wa (128 cols) for the b1 scalar-bias fold.
// ---------------------------------------------------------------------------
__global__ __launch_bounds__(256) void prep_kernel(
    const float* __restrict__ Wa, const float* __restrict__ Wb,
    _Float16* __restrict__ whi, _Float16* __restrict__ wlo,
    float* __restrict__ csA) {
  const int bid = blockIdx.x;          // 0..99 = bk*2 + m
  const int bk = bid >> 1, m = bid & 1;
  const float* src = (m ? Wb : Wa) + (size_t)bk * (WID * WID);
  _Float16* dh = whi + (size_t)bid * WCH;
  _Float16* dl = wlo + (size_t)bid * WCH;
  for (int e = threadIdx.x; e < WCH; e += 256) {
    const int i  = e & 7;
    const int L  = (e >> 3) & 63;
    const int ct = (e >> 9) & 3;
    const int ks = e >> 11;
    const int k  = 16 * ks + 8 * (L >> 5) + i;
    const int j  = 32 * ct + (L & 31);
    const float v = (k < WID && j < WID) ? src[k * WID + j] : 0.0f;
    const _Float16 hi = (_Float16)v;
    dh[e] = hi;
    dl[e] = (_Float16)(v - (float)hi);
  }
  if (!m) {
    for (int col = threadIdx.x; col < NP; col += 256) {
      float s = 0.0f;
      if (col < WID) {
        for (int k = 0; k < WID; ++k) s += src[k * WID + col];
      }
      csA[bk * NP + col] = s;
    }
  }
}

// ---------------------------------------------------------------------------
// First layer: gather 45-wide stencil rows, x0 = relu(flat @ W0)
// ---------------------------------------------------------------------------
__global__ __launch_bounds__(256) void first_layer_kernel(
    const float* __restrict__ inp, const float* __restrict__ W0,
    float* __restrict__ x0) {
  __shared__ float w0s[45 * WID];
  for (int i = threadIdx.x; i < 45 * WID; i += 256) w0s[i] = W0[i];
  __syncthreads();

  const int rq  = threadIdx.x >> 2;
  const int cq  = threadIdx.x & 3;
  const int row = blockIdx.x * 64 + rq;
  const int b   = row >> 8;
  const int t1  = (row >> 4) & 15;
  const int t2  = row & 15;
  const int g1  = 2 * t1, g2 = 2 * t2;
  const int g1m = (g1 + 31) & 31, g2m = (g2 + 31) & 31;
  const float* base = inp + (size_t)b * (32 * 32 * 9);
  const float* p0 = base + ((g1 + 1) * 32 + g2) * 9;
  const float* p1 = base + (g1m * 32 + g2) * 9;
  const float* p2 = base + (g1 * 32 + (g2 + 1)) * 9;
  const float* p3 = base + (g1 * 32 + g2m) * 9;
  const float* p4 = base + (g1 * 32 + g2) * 9;

  float f[45];
#pragma unroll
  for (int qq = 0; qq < 9; ++qq) {
    f[qq]      = p0[qq];
    f[9 + qq]  = p1[qq];
    f[18 + qq] = p2[qq];
    f[27 + qq] = p3[qq];
    f[36 + qq] = p4[qq];
  }

  float acc[25];
#pragma unroll
  for (int j = 0; j < 25; ++j) acc[j] = 0.0f;
  const int j0 = cq * 25;
#pragma unroll
  for (int k = 0; k < 45; ++k) {
    const float fv = f[k];
#pragma unroll
    for (int j = 0; j < 25; ++j) acc[j] += fv * w0s[k * WID + j0 + j];
  }
  float* orow = x0 + (size_t)row * WID + j0;
#pragma unroll
  for (int j = 0; j < 25; ++j) orow[j] = fmaxf(acc[j], 0.0f);
}

// ---------------------------------------------------------------------------
// Chain: 50 residual blocks, split-f16 MFMA 32x32x16 (f32 accum, ~2^-22).
// 512 WGs x 512 thr (8 waves) -> 2 WG/CU, 16 waves/CU.
// Wave (rt,ct) owns rows [32rt,+32) x cols [32ct,+32); acc = f32x16.
// LDS: x hi/lo AND v hi/lo (separate buffers -> only 2 barriers/block),
// f16 [64][128], XOR-swizzled k ^ ((row&15)<<3) -> 2-way-max bank aliasing.
// Weights global->VGPR, all 14 loads batched at kloop top; weight registers
// are dead at kloop exit (NEVER live across a barrier -- R12/R14 cliff).
// fp32 residual x in registers. Per GEMM/wave: 14 gl b128, 14 ds b128, 21 MFMA.
// VGPR budget 64 = the occupancy cliff (m69); verified no-spill at this shape.
// ---------------------------------------------------------------------------
__global__ __launch_bounds__(512, 2) void chain_kernel(
    float* __restrict__ x0,
    const _Float16* __restrict__ whi, const _Float16* __restrict__ wlo,
    const float* __restrict__ csA,
    const float* __restrict__ B1, const float* __restrict__ B2,
    const float* __restrict__ B3, const float* __restrict__ B4,
    const float* __restrict__ M) {
  __shared__ __align__(16) _Float16 xhs[RPW * KP];   // 16 KB
  __shared__ __align__(16) _Float16 xls[RPW * KP];   // 16 KB
  __shared__ __align__(16) _Float16 vhs[RPW * KP];   // 16 KB
  __shared__ __align__(16) _Float16 vls[RPW * KP];   // 16 KB

  const int tid  = threadIdx.x;
  const int lane = tid & 63;
  const int uw   = __builtin_amdgcn_readfirstlane(tid >> 6);  // wave 0..7
  const int rt   = uw >> 2;     // row-tile 0..1
  const int ct   = uw & 3;      // col-tile 0..3
  const int jr   = lane & 31;   // x-row within tile / w-col lane
  const int kg   = lane >> 5;   // k-group 0..1
  const int rbase = blockIdx.x * RPW;

  const int row_x = 32 * rt + jr;            // this lane's x-row
  const int sw    = (row_x & 15) << 3;       // XOR swizzle (f16 units)

  // fill x hi/lo (f32 -> split f16, swizzled); k >= 100 zeroed
  for (int i = tid; i < RPW * KP; i += 512) {
    const int row = i >> 7, k = i & 127;
    const float v = (k < WID) ? x0[(size_t)(rbase + row) * WID + k] : 0.0f;
    const _Float16 hi = (_Float16)v;
    const int a = row * KP + (k ^ ((row & 15) << 3));
    xhs[a] = hi;
    xls[a] = (_Float16)(v - (float)hi);
  }

  // output j coordinates: j = j0g[g] + r, 4 groups of 4 consecutive
  int j0g[4];
#pragma unroll
  for (int g = 0; g < 4; ++g) j0g[g] = 32 * ct + 4 * kg + 8 * g;

  // fp32 residual state: 4 x f32x4 (row fixed = row_x)
  f32x4 xres[4];
#pragma unroll
  for (int g = 0; g < 4; ++g) {
    if (j0g[g] <= WID - 4) {
      xres[g] = *(const f32x4*)&x0[(size_t)(rbase + row_x) * WID + j0g[g]];
    } else {
      xres[g] = (f32x4){0.f, 0.f, 0.f, 0.f};
    }
  }
  __syncthreads();

  f32x16 acc;

  // split-f16 GEMM tile: acc += (wh+wl)^T @ (xh+xl), dropping wl*xl
  auto kloop = [&](const int gidx,
                   const _Float16* __restrict__ xhsrc,
                   const _Float16* __restrict__ xlsrc) {
    const _Float16* gh = whi + (size_t)gidx * WCH + ct * 512;
    const _Float16* gl = wlo + (size_t)gidx * WCH + ct * 512;
    f16x8 wh[KS], wl[KS];
#pragma unroll
    for (int ks = 0; ks < KS; ++ks) {       // batch-issue all global loads
      wh[ks] = *(const f16x8*)&gh[ks * 2048 + lane * 8];
      wl[ks] = *(const f16x8*)&gl[ks * 2048 + lane * 8];
    }
#pragma unroll
    for (int ks = 0; ks < KS; ++ks) {
      const int off = row_x * KP + ((16 * ks + 8 * kg) ^ sw);
      const f16x8 xh = *(const f16x8*)&xhsrc[off];
      const f16x8 xl = *(const f16x8*)&xlsrc[off];
      acc = __builtin_amdgcn_mfma_f32_32x32x16_f16(wh[ks], xh, acc, 0, 0, 0);
      acc = __builtin_amdgcn_mfma_f32_32x32x16_f16(wl[ks], xh, acc, 0, 0, 0);
      acc = __builtin_amdgcn_mfma_f32_32x32x16_f16(wh[ks], xl, acc, 0, 0, 0);
    }
  };

  for (int bk = 0; bk < NB; ++bk) {
    // ---------------- GEMM1: v = 2*relu(2*((x+b1)@Wa) + b2) + b3 ----------
#pragma unroll
    for (int e = 0; e < 16; ++e) acc[e] = 0.0f;
    kloop(bk * 2, xhs, xls);
    {
      const float b1 = B1[bk], b2 = B2[bk], b3 = B3[bk];
#pragma unroll
      for (int g = 0; g < 4; ++g) {
        const f32x4 cs = *(const f32x4*)&csA[bk * NP + j0g[g]];
        f16x4 hv, lv;
#pragma unroll
        for (int r = 0; r < 4; ++r) {
          const float t = 2.0f * (acc[g * 4 + r] + b1 * cs[r]) + b2;
          const float v = 2.0f * fmaxf(t, 0.0f) + b3;
          const _Float16 hi = (_Float16)v;
          hv[r] = hi;
          lv[r] = (_Float16)(v - (float)hi);
        }
        const int a = row_x * KP + (j0g[g] ^ sw);
        *(f16x4*)&vhs[a] = hv;
        *(f16x4*)&vls[a] = lv;
      }
    }
    __syncthreads();            // publish v (x-reads of kloop1 also done)

    // ---------------- GEMM2: x = relu(x + (v@Wb)*m + b4) -------------------
#pragma unroll
    for (int e = 0; e < 16; ++e) acc[e] = 0.0f;
    kloop(bk * 2 + 1, vhs, vls);
    {
      const float b4v = B4[bk], mm = M[bk];
#pragma unroll
      for (int g = 0; g < 4; ++g) {
        f16x4 hv, lv;
#pragma unroll
        for (int r = 0; r < 4; ++r) {
          const float xn = fmaxf(xres[g][r] + acc[g * 4 + r] * mm + b4v, 0.0f);
          xres[g][r] = xn;
          const _Float16 hi = (_Float16)xn;
          hv[r] = hi;
          lv[r] = (_Float16)(xn - (float)hi);
        }
        const int a = row_x * KP + (j0g[g] ^ sw);
        *(f16x4*)&xhs[a] = hv;
        *(f16x4*)&xls[a] = lv;
      }
    }
    __syncthreads();            // publish x(bk+1) (v-reads done)
  }

  // write back fp32 residual state
#pragma unroll
  for (int g = 0; g < 4; ++g) {
    if (j0g[g] <= WID - 4)
      *(f32x4*)&x0[(size_t)(rbase + row_x) * WID + j0g[g]] = xres[g];
  }
}

// ---------------------------------------------------------------------------
// Output head + stencil epilogue. One block per batch image (16x16 grid).
// ---------------------------------------------------------------------------
__global__ __launch_bounds__(256) void out_kernel(
    const float* __restrict__ inp, const float* __restrict__ x0,
    const float* __restrict__ Wout, const float* __restrict__ bout,
    float* __restrict__ out) {
  __shared__ float ys[256 * 4];
  __shared__ float wouts[WID * 4];
  __shared__ float bos[4];
  const int tid = threadIdx.x;
  const int b   = blockIdx.x;

  for (int i = tid; i < WID * 4; i += 256) wouts[i] = Wout[i];
  if (tid < 4) bos[tid] = bout[tid];
  __syncthreads();

  const int row = b * 256 + tid;
  const float* xr = x0 + (size_t)row * WID;
  float a0 = 0.f, a1 = 0.f, a2 = 0.f, a3 = 0.f;
#pragma unroll 4
  for (int k = 0; k < WID; ++k) {
    const float xv = xr[k];
    a0 += xv * wouts[k * 4 + 0];
    a1 += xv * wouts[k * 4 + 1];
    a2 += xv * wouts[k * 4 + 2];
    a3 += xv * wouts[k * 4 + 3];
  }
  ys[tid * 4 + 0] = a0 + bos[0];
  ys[tid * 4 + 1] = a1 + bos[1];
  ys[tid * 4 + 2] = a2 + bos[2];
  ys[tid * 4 + 3] = a3 + bos[3];
  __syncthreads();

  const int i = tid >> 4, j = tid & 15;
  const int ip1 = (i + 1) & 15, im1 = (i + 15) & 15;
  const int jp1 = (j + 1) & 15, jm1 = (j + 15) & 15;
  auto Y = [&](int a, int c, int comp) { return ys[(((a << 4) | c) << 2) + comp]; };
  const float y0 = Y(i, j, 0), y1 = Y(i, j, 1), y2 = Y(i, j, 2), y3 = Y(i, j, 3);
  const float right_c = y0 / (Y(ip1, j, 1) + y0);
  const float left_c  = y1 / (y1 + Y(im1, j, 0));
  const float up_c    = y2 / (y2 + Y(i, jp1, 3));
  const float down_c  = y3 / (Y(i, jm1, 2) + y3);

  const float* base = inp + (size_t)b * (32 * 32 * 9);
  const int g1 = 2 * i + 1, g1m = (2 * i + 31) & 31;
  const int g2 = 2 * j + 1, g2m = (2 * j + 31) & 31;
  const float* oo = base + (g1 * 32 + g2) * 9;
  const float* oi = base + (g1 * 32 + g2m) * 9;
  const float* io = base + (g1m * 32 + g2) * 9;
  const float* ii = base + (g1m * 32 + g2m) * 9;
  const float ru = -(oo[0] + oo[3] * right_c + oo[1] * up_c) / oo[4];
  const float rd = -(oi[2] + oi[5] * right_c + oi[1] * down_c) / oi[4];
  const float lu = -(io[6] + io[3] * left_c + io[7] * up_c) / io[4];
  const float ld = -(ii[8] + ii[5] * left_c + ii[7] * down_c) / ii[4];

  float* o = out + (size_t)row * 9;
  o[0] = ld;     o[1] = left_c;  o[2] = lu;
  o[3] = down_c; o[4] = 1.0f;    o[5] = up_c;
  o[6] = rd;     o[7] = right_c; o[8] = ru;
}

// ---------------------------------------------------------------------------
extern "C" void kernel_launch(void* const* d_in, const int* in_sizes, int n_in,
                              void* d_out, int out_size, void* d_ws, size_t ws_size,
                              hipStream_t stream) {
  const float* inp  = (const float*)d_in[0];
  const float* W0   = (const float*)d_in[1];
  const float* Wa   = (const float*)d_in[2];
  const float* Wb   = (const float*)d_in[3];
  const float* B1   = (const float*)d_in[4];
  const float* B2   = (const float*)d_in[5];
  const float* B3   = (const float*)d_in[6];
  const float* B4   = (const float*)d_in[7];
  const float* M    = (const float*)d_in[8];
  const float* Wout = (const float*)d_in[9];
  const float* bout = (const float*)d_in[10];
  float* out = (float*)d_out;

  float* ws     = (float*)d_ws;
  float* x0     = ws;                              // 3,276,800 f32
  _Float16* whi = (_Float16*)(ws + 3276800);       // 100*14336 f16 = 716,800 f32
  _Float16* wlo = (_Float16*)(ws + 3276800 + 716800);
  float* csA    = ws + 3276800 + 716800 + 716800;  // 50*128 f32

  hipLaunchKernelGGL(prep_kernel, dim3(100), dim3(256), 0, stream,
                     Wa, Wb, whi, wlo, csA);
  hipLaunchKernelGGL(first_layer_kernel, dim3(ROWS / 64), dim3(256), 0, stream,
                     inp, W0, x0);
  hipLaunchKernelGGL(chain_kernel, dim3(ROWS / RPW), dim3(512), 0, stream,
                     x0, whi, wlo, csA, B1, B2, B3, B4, M);
  hipLaunchKernelGGL(out_kernel, dim3(BATCH), dim3(256), 0, stream,
                     inp, x0, Wout, bout, out);
}